// Round 10
// baseline (9957.072 us; speedup 1.0000x reference)
//
#include <hip/hip_runtime.h>
#include <math.h>

// Problem constants (from reference)
constexpr int T_ = 131072;
constexpr int E_ = 512;
constexpr int H_ = 512;
constexpr int K_ = 1024;
constexpr int L_ = 128;
constexpr int CAND_CAP = 16384;

typedef __attribute__((ext_vector_type(4))) float f32x4;

// Grid sizes
constexpr int NB_GRU     = 384;
constexpr unsigned NB_MEGA    = NB_GRU + 2 * (T_ / 4);   // 65920
constexpr unsigned NB_COLLECT = T_ / 256;                // 512
constexpr unsigned NB_ATTN    = 128;

// Workspace layout (element offsets; floats unless noted)
constexpr size_t OFF_V     = 0;                    // 512 f
constexpr size_t OFF_ALPHA = 512;                  // 131072 f (reused as attn partials)
constexpr size_t OFF_HIST1 = OFF_ALPHA + T_;       // 65536 u32
constexpr size_t OFF_CNT   = OFF_HIST1 + 65536;    // 2 u32 (def count, cand count)
constexpr size_t OFF_DONE  = OFF_CNT + 2;          // 4 u32 (tickets: mega, collect, attn)
constexpr size_t OFF_INFO  = OFF_DONE + 4;         // 8 u32
constexpr size_t OFF_VALS  = OFF_INFO + 8;         // 1024 f
constexpr size_t OFF_IDX   = OFF_VALS + K_;        // 1024 i32
constexpr size_t OFF_CANDV = OFF_IDX + K_;         // 16384 f
constexpr size_t OFF_CANDI = OFF_CANDV + CAND_CAP; // 16384 i32
constexpr size_t OFF_GI    = OFF_CANDI + CAND_CAP; // 1536 f
constexpr size_t OFF_GH    = OFF_GI + 3 * H_;      // 1536 f

// Zeroed-per-call contiguous region: hist1 + cnt + done
constexpr int ZERO_N = 65536 + 2 + 4;

// Output layout: score(1) | h_new(512) | vs_new((T+1)*512) | hs_new((T+1)*512)
constexpr size_t OUT_VS = 513;
constexpr size_t OUT_HS = 513 + (size_t)(T_ + 1) * E_;

// JOURNAL (measured):
//  R4: low-cardinality chunk atomic in mega -> 40K-deep serialization, 860us. NEVER.
//  R5: separate-kernel tail + parallel LDS scans = 244.9us.
//  R6: software spin grid-barriers (512 blocks, cross-XCD) = +43us/barrier. NEVER spin.
//  R7: mega 2 rows/wave neutral (not issue-depth-limited).
//  R8: GRU folded into mega as leading blocks = 235.75 (-9).
//  R9: single radix pass + candidate rank-resolve = 227.56 (-8).
//  R4 profile: mega FETCH=262MB for 512MB input -> NT stores preserve L3 input
//      residency (plain stores would evict it). KEEP NT stores.
//  This round: last-finisher folds (threadFenceReduction idiom, no spinning):
//      scan->mega, resolve->collect, final->attn. 7 launches -> 4.

__device__ __forceinline__ unsigned fkey(float f) {
    unsigned u = __float_as_uint(f);
    return (u & 0x80000000u) ? ~u : (u | 0x80000000u);  // ascending key == ascending float
}

// Returns true for exactly one block: the last to arrive. All prior blocks'
// global stores are visible to the winner (fence + ACQ_REL ticket chain).
__device__ __forceinline__ bool last_finisher(unsigned* ticket, unsigned nblocks,
                                              unsigned* s_t) {
    __threadfence();
    __syncthreads();
    if (threadIdx.x == 0)
        *s_t = __hip_atomic_fetch_add(ticket, 1u, __ATOMIC_ACQ_REL,
                                      __HIP_MEMORY_SCOPE_AGENT);
    __syncthreads();
    if (*s_t != nblocks - 1) return false;
    __threadfence();
    return true;
}

// Last block: v = mean(emb[topic]) (two 512-thread halves, deterministic order).
// Other blocks: zero hist1+cnt+done (ZERO_N u32, contiguous).
__global__ __launch_bounds__(1024) void k_init(const int* __restrict__ topic,
                                               const float* __restrict__ emb,
                                               float* __restrict__ ws_v,
                                               unsigned* __restrict__ zero_base,
                                               float* __restrict__ out) {
    if (blockIdx.x == gridDim.x - 1) {
        __shared__ float part[512];
        int t = threadIdx.x;
        int e = t & 511, g = t >> 9;       // g in {0,1}
        float s = 0.f;
        #pragma unroll 8
        for (int l = g * 64; l < g * 64 + 64; ++l) {
            int tp = topic[l];
            s += emb[(size_t)tp * E_ + e];
        }
        if (g == 1) part[e] = s;
        __syncthreads();
        if (g == 0) {
            float v = (s + part[e]) * (1.0f / L_);
            ws_v[e] = v;
            out[OUT_VS + (size_t)T_ * E_ + e] = v;  // vs_new last row
        }
    } else {
        int i = blockIdx.x * blockDim.x + threadIdx.x;
        if (i < ZERO_N) zero_base[i] = 0u;
    }
}

// Parallel descending scan over the 65536-bin histogram: find bin1 containing
// the Kth largest + count_above. Run by 256 threads; ps = 258 u32 shared.
__device__ void scan_body(const unsigned* __restrict__ hist,
                          unsigned* __restrict__ info, unsigned* ps) {
    int t = threadIdx.x;
    unsigned Kwant = (unsigned)K_;
    unsigned base = 65536u - (unsigned)(t + 1) * 256u;
    unsigned s = 0;
    for (int j = 0; j < 256; ++j) s += hist[base + j];
    ps[t] = s;
    __syncthreads();
    #pragma unroll
    for (int off = 1; off < 256; off <<= 1) {
        unsigned v = (t >= off) ? ps[t - off] : 0u;
        __syncthreads();
        ps[t] += v;
        __syncthreads();
    }
    unsigned incl = ps[t], excl = incl - s;
    if (excl < Kwant && incl >= Kwant) { ps[256] = (unsigned)t; ps[257] = excl; }
    __syncthreads();
    unsigned c = ps[256];
    unsigned above = ps[257];
    unsigned Kw2 = Kwant - above;
    unsigned bin = 65535u - c * 256u - (unsigned)t;
    unsigned b = hist[bin];
    __syncthreads();
    ps[t] = b;
    __syncthreads();
    #pragma unroll
    for (int off = 1; off < 256; off <<= 1) {
        unsigned v = (t >= off) ? ps[t - off] : 0u;
        __syncthreads();
        ps[t] += v;
        __syncthreads();
    }
    unsigned inc2 = ps[t], ex2 = inc2 - b;
    if (ex2 < Kw2 && inc2 >= Kw2) {
        info[0] = bin;
        info[1] = above + ex2;
    }
}

// Mega kernel: {GRU gates (blocks 0..383)} + {vs copy + alpha dot + hist1} +
// {hs copy} + {scan, by the last-finishing block}. NT float4 loads+stores
// (KEEP: preserves L3 input residency), shuffle-rotate realignment.
// ONE atomic per row to the 65536-bin hist (NEVER low-cardinality - R4).
__global__ __launch_bounds__(256) void k_mega(const float* __restrict__ vs,
                                              const float* __restrict__ hs,
                                              const float* __restrict__ ws_v,
                                              float* __restrict__ alpha,
                                              unsigned* __restrict__ hist1,
                                              const float* __restrict__ wih,
                                              const float* __restrict__ whh,
                                              const float* __restrict__ bih,
                                              const float* __restrict__ bhh,
                                              const float* __restrict__ score_s,
                                              const float* __restrict__ h_in,
                                              float* __restrict__ gi,
                                              float* __restrict__ gh,
                                              unsigned* __restrict__ done,
                                              unsigned* __restrict__ info,
                                              float* __restrict__ out) {
    __shared__ float x[1025 + 512];
    __shared__ unsigned s_t;
    int t = threadIdx.x;
    int wave = t >> 6, lane = t & 63;
    int b = blockIdx.x;
    if (b < NB_GRU) {
        // ---- GRU gates: one gate-row per wave ----
        float ss = score_s[0];
        float pos = ss >= 0.5f ? 1.f : 0.f;
        for (int c = t; c < 1025; c += 256) {
            float xv;
            if (c < 512)       xv = ws_v[c] * pos;
            else if (c < 1024) xv = ws_v[c - 512] * (1.f - pos);
            else               xv = ss;
            x[c] = xv;
        }
        for (int c = t; c < 512; c += 256) x[1025 + c] = h_in[c];
        __syncthreads();
        int row = b * 4 + wave;
        const float* wr = wih + (size_t)row * 1025;
        float s1 = 0.f;
        for (int c = lane; c < 1025; c += 64) s1 = fmaf(wr[c], x[c], s1);
        const float* hr = whh + (size_t)row * 512;
        float s2 = 0.f;
        #pragma unroll
        for (int c = lane; c < 512; c += 64) s2 = fmaf(hr[c], x[1025 + c], s2);
        #pragma unroll
        for (int m = 32; m; m >>= 1) {
            s1 += __shfl_xor(s1, m, 64);
            s2 += __shfl_xor(s2, m, 64);
        }
        if (lane == 0) { gi[row] = s1 + bih[row]; gh[row] = s2 + bhh[row]; }
    } else {
        // ---- Copy + alpha halves ----
        int bb = b - NB_GRU;
        bool is_vs = bb < (T_ / 4);
        int row = (is_vs ? bb : bb - T_ / 4) * 4 + wave;
        const f32x4* src4 = (const f32x4*)((is_vs ? vs : hs) + (size_t)row * E_);
        f32x4 a0 = __builtin_nontemporal_load(&src4[lane]);
        f32x4 a1 = __builtin_nontemporal_load(&src4[lane + 64]);
        if (is_vs) {
            const f32x4* v4 = (const f32x4*)ws_v;
            f32x4 b0 = v4[lane];
            f32x4 b1 = v4[lane + 64];
            float dot = 0.f;
            dot = fmaf(a0.x, b0.x, dot); dot = fmaf(a0.y, b0.y, dot);
            dot = fmaf(a0.z, b0.z, dot); dot = fmaf(a0.w, b0.w, dot);
            dot = fmaf(a1.x, b1.x, dot); dot = fmaf(a1.y, b1.y, dot);
            dot = fmaf(a1.z, b1.z, dot); dot = fmaf(a1.w, b1.w, dot);
            #pragma unroll
            for (int m = 32; m; m >>= 1) dot += __shfl_xor(dot, m, 64);
            if (lane == 0) {
                alpha[row] = dot;
                atomicAdd(&hist1[fkey(dot) >> 16], 1u);
            }
        }
        // Shuffle-rotate realignment
        int nl = (lane + 1) & 63;
        float n0x = __shfl(a0.x, nl, 64), n0y = __shfl(a0.y, nl, 64), n0z = __shfl(a0.z, nl, 64);
        float n1x = __shfl(a1.x, nl, 64), n1y = __shfl(a1.y, nl, 64), n1z = __shfl(a1.z, nl, 64);
        float* dst = out + (is_vs ? OUT_VS : OUT_HS) + (size_t)row * E_;
        f32x4* d4 = (f32x4*)(dst + 3);            // 16B-aligned
        bool last = (lane == 63);
        f32x4 lo;
        lo.x = a0.w;
        lo.y = last ? n1x : n0x;   // lane 63: e[256..258] = a1.xyz of lane 0
        lo.z = last ? n1y : n0y;
        lo.w = last ? n1z : n0z;
        __builtin_nontemporal_store(lo, &d4[lane]);
        if (!last) {
            f32x4 hi;
            hi.x = a1.w; hi.y = n1x; hi.z = n1y; hi.w = n1z;
            __builtin_nontemporal_store(hi, &d4[lane + 64]);
        }
        if (lane == 0) { dst[0] = a0.x; dst[1] = a0.y; dst[2] = a0.z; }
        if (last) dst[511] = a1.w;
    }
    // ---- last-finisher: threshold-bin scan ----
    if (last_finisher(&done[0], NB_MEGA, &s_t)) {
        scan_body(hist1, info, (unsigned*)x);
    }
}

// Collect pass: definite top-K (key>>16 > bin1) straight into vals/idx;
// threshold-bin values into candidate buffer. Last-finishing block runs the
// exact stable-rank resolve (O(nc^2), nc ~ tens) for the remaining slots.
__global__ __launch_bounds__(256) void k_collect(const float* __restrict__ alpha,
                                                 const unsigned* __restrict__ info,
                                                 unsigned* __restrict__ cnt,
                                                 unsigned* __restrict__ done,
                                                 float* __restrict__ vals,
                                                 int* __restrict__ idx,
                                                 float* __restrict__ candv,
                                                 int* __restrict__ candi) {
    __shared__ unsigned s_t;
    int i = blockIdx.x * blockDim.x + threadIdx.x;
    float a = alpha[i];
    unsigned hb = fkey(a) >> 16;
    unsigned bin1 = info[0];
    if (hb > bin1) {
        unsigned p = atomicAdd(&cnt[0], 1u);
        vals[p] = a; idx[p] = i;
    } else if (hb == bin1) {
        unsigned q = atomicAdd(&cnt[1], 1u);
        if (q < (unsigned)CAND_CAP) { candv[q] = a; candi[q] = i; }
    }
    // ---- last-finisher: rank-resolve ----
    if (last_finisher(&done[1], NB_COLLECT, &s_t)) {
        int t = threadIdx.x;
        unsigned nc = cnt[1] < (unsigned)CAND_CAP ? cnt[1] : (unsigned)CAND_CAP;
        unsigned ndef = cnt[0];
        unsigned k2 = (unsigned)K_ - ndef;
        for (unsigned ii = t; ii < nc; ii += 256) {
            unsigned ki = fkey(candv[ii]);
            unsigned greater = 0, eqb = 0;
            for (unsigned j = 0; j < nc; ++j) {
                unsigned kj = fkey(candv[j]);
                greater += (kj > ki) ? 1u : 0u;
                eqb += (kj == ki && j < ii) ? 1u : 0u;
            }
            unsigned r = greater + eqb;
            if (r < k2) { vals[ndef + r] = candv[ii]; idx[ndef + r] = candi[ii]; }
        }
    }
}

// Fused softmax + attention gather; last-finishing block runs GRU-finalize +
// score. 128 blocks x 512 threads.
__global__ __launch_bounds__(512) void k_attn(const float* __restrict__ hs,
                                              const float* __restrict__ vals,
                                              const int* __restrict__ idx,
                                              float* __restrict__ part,
                                              unsigned* __restrict__ done,
                                              const float* __restrict__ gi,
                                              const float* __restrict__ gh,
                                              const float* __restrict__ h_in,
                                              const float* __restrict__ ws_v,
                                              const float* __restrict__ w_score,
                                              const float* __restrict__ b_score,
                                              float* __restrict__ out) {
    __shared__ float red[512];
    __shared__ unsigned s_t;
    int t = threadIdx.x, j = blockIdx.x;
    float v0 = vals[t], v1 = vals[t + 512];
    red[t] = fmaxf(v0, v1);
    __syncthreads();
    for (int s = 256; s > 0; s >>= 1) { if (t < s) red[t] = fmaxf(red[t], red[t + s]); __syncthreads(); }
    float m = red[0];
    __syncthreads();
    red[t] = expf(v0 - m) + expf(v1 - m);
    __syncthreads();
    for (int s = 256; s > 0; s >>= 1) { if (t < s) red[t] += red[t + s]; __syncthreads(); }
    float S = red[0];
    float acc = 0.f;
    #pragma unroll
    for (int k = j * 8; k < j * 8 + 8; ++k) {
        float w = expf(vals[k] - m) / S;
        acc = fmaf(w, hs[(size_t)idx[k] * E_ + t], acc);
    }
    part[(size_t)j * E_ + t] = acc;
    // ---- last-finisher: GRU-finalize + score ----
    if (last_finisher(&done[2], NB_ATTN, &s_t)) {
        __syncthreads();   // red[] reuse
        float rr = 1.f / (1.f + expf(-(gi[t] + gh[t])));
        float z = 1.f / (1.f + expf(-(gi[H_ + t] + gh[H_ + t])));
        float n = tanhf(gi[2 * H_ + t] + rr * gh[2 * H_ + t]);
        float hp = h_in[t];
        float hn = (1.f - z) * n + z * hp;
        out[1 + t] = hn;                          // h_new
        out[OUT_HS + (size_t)T_ * E_ + t] = hn;   // hs_new last row
        float attn = 0.f;
        for (int jj = 0; jj < 128; ++jj) attn += part[(size_t)jj * E_ + t];
        float d = ws_v[t] * w_score[t] + attn * w_score[512 + t] + hp * w_score[1024 + t];
        if (t == 0) d += 1024.0f * w_score[1536] + b_score[0];
        red[t] = d;
        __syncthreads();
        for (int s = 256; s > 0; s >>= 1) { if (t < s) red[t] += red[t + s]; __syncthreads(); }
        if (t == 0) out[0] = red[0];
    }
}

extern "C" void kernel_launch(void* const* d_in, const int* in_sizes, int n_in,
                              void* d_out, int out_size, void* d_ws, size_t ws_size,
                              hipStream_t stream) {
    const int*   topic   = (const int*)d_in[0];
    const float* score_s = (const float*)d_in[1];
    const float* emb     = (const float*)d_in[2];
    const float* h_in    = (const float*)d_in[3];
    const float* vs      = (const float*)d_in[4];
    const float* hs      = (const float*)d_in[5];
    const float* w_ih    = (const float*)d_in[6];
    const float* w_hh    = (const float*)d_in[7];
    const float* b_ih    = (const float*)d_in[8];
    const float* b_hh    = (const float*)d_in[9];
    const float* w_score = (const float*)d_in[10];
    const float* b_score = (const float*)d_in[11];
    float* out = (float*)d_out;

    float*    wsf   = (float*)d_ws;
    float*    v_ws  = wsf + OFF_V;
    float*    alpha = wsf + OFF_ALPHA;
    unsigned* hist1 = (unsigned*)(wsf + OFF_HIST1);
    unsigned* cnt   = (unsigned*)(wsf + OFF_CNT);
    unsigned* done  = (unsigned*)(wsf + OFF_DONE);
    unsigned* info  = (unsigned*)(wsf + OFF_INFO);
    float*    vals  = wsf + OFF_VALS;
    int*      idx   = (int*)(wsf + OFF_IDX);
    float*    candv = wsf + OFF_CANDV;
    int*      candi = (int*)(wsf + OFF_CANDI);
    float*    part  = wsf + OFF_ALPHA;  // alpha dead after k_collect; reuse as partials
    float*    gi    = wsf + OFF_GI;
    float*    gh    = wsf + OFF_GH;

    // 1) v + zero-init (blocks 0..64 zero ZERO_N u32; block 65 computes v)
    hipLaunchKernelGGL(k_init, dim3(66), dim3(1024), 0, stream,
                       topic, emb, v_ws, hist1, out);
    // 2) fused GRU gates + copies + alpha + hist1 + scan (last finisher)
    hipLaunchKernelGGL(k_mega, dim3(NB_MEGA), dim3(256), 0, stream,
                       vs, hs, v_ws, alpha, hist1,
                       w_ih, w_hh, b_ih, b_hh, score_s, h_in, gi, gh,
                       done, info, out);
    // 3) collect top-K + candidates + rank-resolve (last finisher)
    hipLaunchKernelGGL(k_collect, dim3(NB_COLLECT), dim3(256), 0, stream,
                       alpha, info, cnt, done, vals, idx, candv, candi);
    // 4) softmax + attention gather + GRU-finalize + score (last finisher)
    hipLaunchKernelGGL(k_attn, dim3(NB_ATTN), dim3(512), 0, stream,
                       hs, vals, idx, part, done,
                       gi, gh, h_in, v_ws, w_score, b_score, out);
}

// Round 11
// 225.929 us; speedup vs baseline: 44.0717x; 44.0717x over previous
//
#include <hip/hip_runtime.h>
#include <math.h>

// Problem constants (from reference)
constexpr int T_ = 131072;
constexpr int E_ = 512;
constexpr int H_ = 512;
constexpr int K_ = 1024;
constexpr int L_ = 128;
constexpr int CAND_CAP = 16384;

typedef __attribute__((ext_vector_type(4))) float f32x4;

// Grid sizes
constexpr int NB_GRU = 384;
constexpr unsigned NB_MEGA = NB_GRU + 2 * (T_ / 4);   // 65920

// Workspace layout (element offsets; floats unless noted)
constexpr size_t OFF_V     = 0;                    // 512 f
constexpr size_t OFF_ALPHA = 512;                  // 131072 f
constexpr size_t OFF_HIST1 = OFF_ALPHA + T_;       // 65536 u32
constexpr size_t OFF_CNT   = OFF_HIST1 + 65536;    // 2 u32 (def count, cand count)
constexpr size_t OFF_VALS  = OFF_CNT + 2;          // 1024 f
constexpr size_t OFF_IDX   = OFF_VALS + K_;        // 1024 i32
constexpr size_t OFF_CANDV = OFF_IDX + K_;         // 16384 f
constexpr size_t OFF_CANDI = OFF_CANDV + CAND_CAP; // 16384 i32
constexpr size_t OFF_GI    = OFF_CANDI + CAND_CAP; // 1536 f
constexpr size_t OFF_GH    = OFF_GI + 3 * H_;      // 1536 f

// Zeroed-per-call contiguous region: hist1 + cnt
constexpr int ZERO_N = 65536 + 2;

// Output layout: score(1) | h_new(512) | vs_new((T+1)*512) | hs_new((T+1)*512)
constexpr size_t OUT_VS = 513;
constexpr size_t OUT_HS = 513 + (size_t)(T_ + 1) * E_;

// JOURNAL (measured):
//  R4:  low-cardinality chunk atomic in mega -> 40K-deep serialization, 860us. NEVER.
//  R5:  separate-kernel tail + parallel LDS scans = 244.9us.
//  R6:  spin grid-barriers (512 blocks, cross-XCD) = +43us each. NEVER spin.
//  R7:  mega 2 rows/wave neutral (not issue-depth-limited).
//  R8:  GRU folded into mega as leading blocks = 235.75 (-9).
//  R9:  single radix pass + candidate rank-resolve = 227.56 (-8). KNOWN GOOD.
//  R10: last-finisher (__threadfence + device ACQ_REL ticket) in ALL 65920 mega
//       blocks = 9957us (44x!). Agent-scope fence => per-XCD L2 writeback; 65K
//       same-address RMWs serialize. NEVER per-block device fences/tickets in
//       large grids. Kernel-boundary sync is the ONLY cheap global sync here.
//  R4 profile: NT stores preserve L3 input residency (FETCH 267MB vs 512MB
//       input). KEEP NT. WRITE=554MB (+8% seam overwrite) is structural.
//  This round: revert to R9 + (a) collect blocks compute bin1 redundantly
//       (kills scan launch), (b) attn blocks atomicAdd score pieces into out[0],
//       extra block does GRU-finalize (kills final launch + part[] roundtrip).

__device__ __forceinline__ unsigned fkey(float f) {
    unsigned u = __float_as_uint(f);
    return (u & 0x80000000u) ? ~u : (u | 0x80000000u);  // ascending key == ascending float
}

// Last block: v = mean(emb[topic]) (two 512-thread halves, deterministic order)
// + zero out[0] (score accumulator). Other blocks: zero hist1+cnt.
__global__ __launch_bounds__(1024) void k_init(const int* __restrict__ topic,
                                               const float* __restrict__ emb,
                                               float* __restrict__ ws_v,
                                               unsigned* __restrict__ zero_base,
                                               float* __restrict__ out) {
    if (blockIdx.x == gridDim.x - 1) {
        __shared__ float part[512];
        int t = threadIdx.x;
        int e = t & 511, g = t >> 9;       // g in {0,1}
        float s = 0.f;
        #pragma unroll 8
        for (int l = g * 64; l < g * 64 + 64; ++l) {
            int tp = topic[l];
            s += emb[(size_t)tp * E_ + e];
        }
        if (g == 1) part[e] = s;
        __syncthreads();
        if (g == 0) {
            float v = (s + part[e]) * (1.0f / L_);
            ws_v[e] = v;
            out[OUT_VS + (size_t)T_ * E_ + e] = v;  // vs_new last row
            if (e == 0) out[0] = 0.f;               // score accumulator
        }
    } else {
        int i = blockIdx.x * blockDim.x + threadIdx.x;
        if (i < ZERO_N) zero_base[i] = 0u;
    }
}

// Mega kernel (R9-verified, byte-identical): {GRU gates (blocks 0..383)} +
// {vs copy + alpha dot + hist1} + {hs copy}. NT float4 loads+stores (KEEP:
// preserves L3 input residency), shuffle-rotate realignment. ONE atomic per
// row to the 65536-bin hist (NEVER low-cardinality - R4).
__global__ __launch_bounds__(256) void k_mega(const float* __restrict__ vs,
                                              const float* __restrict__ hs,
                                              const float* __restrict__ ws_v,
                                              float* __restrict__ alpha,
                                              unsigned* __restrict__ hist1,
                                              const float* __restrict__ wih,
                                              const float* __restrict__ whh,
                                              const float* __restrict__ bih,
                                              const float* __restrict__ bhh,
                                              const float* __restrict__ score_s,
                                              const float* __restrict__ h_in,
                                              float* __restrict__ gi,
                                              float* __restrict__ gh,
                                              float* __restrict__ out) {
    __shared__ float x[1025 + 512];
    int t = threadIdx.x;
    int wave = t >> 6, lane = t & 63;
    int b = blockIdx.x;
    if (b < NB_GRU) {
        // ---- GRU gates: one gate-row per wave ----
        float ss = score_s[0];
        float pos = ss >= 0.5f ? 1.f : 0.f;
        for (int c = t; c < 1025; c += 256) {
            float xv;
            if (c < 512)       xv = ws_v[c] * pos;
            else if (c < 1024) xv = ws_v[c - 512] * (1.f - pos);
            else               xv = ss;
            x[c] = xv;
        }
        for (int c = t; c < 512; c += 256) x[1025 + c] = h_in[c];
        __syncthreads();
        int row = b * 4 + wave;
        const float* wr = wih + (size_t)row * 1025;
        float s1 = 0.f;
        for (int c = lane; c < 1025; c += 64) s1 = fmaf(wr[c], x[c], s1);
        const float* hr = whh + (size_t)row * 512;
        float s2 = 0.f;
        #pragma unroll
        for (int c = lane; c < 512; c += 64) s2 = fmaf(hr[c], x[1025 + c], s2);
        #pragma unroll
        for (int m = 32; m; m >>= 1) {
            s1 += __shfl_xor(s1, m, 64);
            s2 += __shfl_xor(s2, m, 64);
        }
        if (lane == 0) { gi[row] = s1 + bih[row]; gh[row] = s2 + bhh[row]; }
        return;
    }
    // ---- Copy + alpha halves ----
    b -= NB_GRU;
    bool is_vs = b < (T_ / 4);
    int row = (is_vs ? b : b - T_ / 4) * 4 + wave;
    const f32x4* src4 = (const f32x4*)((is_vs ? vs : hs) + (size_t)row * E_);
    f32x4 a0 = __builtin_nontemporal_load(&src4[lane]);
    f32x4 a1 = __builtin_nontemporal_load(&src4[lane + 64]);
    if (is_vs) {
        const f32x4* v4 = (const f32x4*)ws_v;
        f32x4 b0 = v4[lane];
        f32x4 b1 = v4[lane + 64];
        float dot = 0.f;
        dot = fmaf(a0.x, b0.x, dot); dot = fmaf(a0.y, b0.y, dot);
        dot = fmaf(a0.z, b0.z, dot); dot = fmaf(a0.w, b0.w, dot);
        dot = fmaf(a1.x, b1.x, dot); dot = fmaf(a1.y, b1.y, dot);
        dot = fmaf(a1.z, b1.z, dot); dot = fmaf(a1.w, b1.w, dot);
        #pragma unroll
        for (int m = 32; m; m >>= 1) dot += __shfl_xor(dot, m, 64);
        if (lane == 0) {
            alpha[row] = dot;
            atomicAdd(&hist1[fkey(dot) >> 16], 1u);
        }
    }
    // Shuffle-rotate realignment
    int nl = (lane + 1) & 63;
    float n0x = __shfl(a0.x, nl, 64), n0y = __shfl(a0.y, nl, 64), n0z = __shfl(a0.z, nl, 64);
    float n1x = __shfl(a1.x, nl, 64), n1y = __shfl(a1.y, nl, 64), n1z = __shfl(a1.z, nl, 64);
    float* dst = out + (is_vs ? OUT_VS : OUT_HS) + (size_t)row * E_;
    f32x4* d4 = (f32x4*)(dst + 3);            // 16B-aligned
    bool last = (lane == 63);
    f32x4 lo;
    lo.x = a0.w;
    lo.y = last ? n1x : n0x;   // lane 63: e[256..258] = a1.xyz of lane 0
    lo.z = last ? n1y : n0y;
    lo.w = last ? n1z : n0z;
    __builtin_nontemporal_store(lo, &d4[lane]);
    if (!last) {
        f32x4 hi;
        hi.x = a1.w; hi.y = n1x; hi.z = n1y; hi.w = n1z;
        __builtin_nontemporal_store(hi, &d4[lane + 64]);
    }
    if (lane == 0) { dst[0] = a0.x; dst[1] = a0.y; dst[2] = a0.z; }
    if (last) dst[511] = a1.w;
}

// Collect pass with REDUNDANT per-block scan: every block computes bin1 from
// hist1 (L2-resident, ~4us aggregate) - no separate scan launch, no info dep.
// Then: definite top-K (key>>16 > bin1) -> vals/idx; threshold-bin -> cand buf.
__global__ __launch_bounds__(256) void k_collect(const float* __restrict__ alpha,
                                                 const unsigned* __restrict__ hist1,
                                                 unsigned* __restrict__ cnt,
                                                 float* __restrict__ vals,
                                                 int* __restrict__ idx,
                                                 float* __restrict__ candv,
                                                 int* __restrict__ candi) {
    __shared__ unsigned ps[258];
    int t = threadIdx.x;
    // ---- redundant scan: find bin1 (bin containing the Kth largest) ----
    unsigned base = 65536u - (unsigned)(t + 1) * 256u;
    unsigned s = 0;
    for (int j = 0; j < 256; ++j) s += hist1[base + j];
    ps[t] = s;
    __syncthreads();
    #pragma unroll
    for (int off = 1; off < 256; off <<= 1) {
        unsigned v = (t >= off) ? ps[t - off] : 0u;
        __syncthreads();
        ps[t] += v;
        __syncthreads();
    }
    unsigned incl = ps[t], excl = incl - s;
    if (excl < (unsigned)K_ && incl >= (unsigned)K_) { ps[256] = (unsigned)t; ps[257] = excl; }
    __syncthreads();
    unsigned c = ps[256];
    unsigned Kw2 = (unsigned)K_ - ps[257];
    unsigned bin = 65535u - c * 256u - (unsigned)t;
    unsigned bv = hist1[bin];
    __syncthreads();
    ps[t] = bv;
    __syncthreads();
    #pragma unroll
    for (int off = 1; off < 256; off <<= 1) {
        unsigned v = (t >= off) ? ps[t - off] : 0u;
        __syncthreads();
        ps[t] += v;
        __syncthreads();
    }
    unsigned inc2 = ps[t], ex2 = inc2 - bv;
    if (ex2 < Kw2 && inc2 >= Kw2) ps[256] = bin;   // winner publishes bin1
    __syncthreads();
    unsigned bin1 = ps[256];
    // ---- classify this block's 256 elements ----
    int i = blockIdx.x * 256 + t;
    float a = alpha[i];
    unsigned hb = fkey(a) >> 16;
    if (hb > bin1) {
        unsigned p = atomicAdd(&cnt[0], 1u);
        vals[p] = a; idx[p] = i;
    } else if (hb == bin1) {
        unsigned q = atomicAdd(&cnt[1], 1u);
        if (q < (unsigned)CAND_CAP) { candv[q] = a; candi[q] = i; }
    }
}

// Exact stable-rank selection among candidates (O(nc^2), nc ~ tens).
__global__ __launch_bounds__(256) void k_resolve(const float* __restrict__ candv,
                                                 const int* __restrict__ candi,
                                                 const unsigned* __restrict__ cnt,
                                                 float* __restrict__ vals,
                                                 int* __restrict__ idx) {
    int t = threadIdx.x;
    unsigned nc = cnt[1] < (unsigned)CAND_CAP ? cnt[1] : (unsigned)CAND_CAP;
    unsigned ndef = cnt[0];
    unsigned k2 = (unsigned)K_ - ndef;
    for (unsigned i = t; i < nc; i += 256) {
        unsigned ki = fkey(candv[i]);
        unsigned greater = 0, eqb = 0;
        for (unsigned j = 0; j < nc; ++j) {
            unsigned kj = fkey(candv[j]);
            greater += (kj > ki) ? 1u : 0u;
            eqb += (kj == ki && j < i) ? 1u : 0u;
        }
        unsigned r = greater + eqb;
        if (r < k2) { vals[ndef + r] = candv[i]; idx[ndef + r] = candi[i]; }
    }
}

// Fused softmax + attention gather + score accumulation + GRU finalize.
// Blocks 0..127: softmax stats (redundant, L2-resident vals), gather 8 rows,
// dot partial with w_score[512:1024] slice, block-reduce, atomicAdd out[0].
// Block 128: GRU finalize (h_new, hs last row) + base score terms -> out[0].
// out[0] zeroed by k_init each call; ~1e-7 FP-order jitter, threshold 9.2e-2.
__global__ __launch_bounds__(512) void k_attn(const float* __restrict__ hs,
                                              const float* __restrict__ vals,
                                              const int* __restrict__ idx,
                                              const float* __restrict__ gi,
                                              const float* __restrict__ gh,
                                              const float* __restrict__ h_in,
                                              const float* __restrict__ ws_v,
                                              const float* __restrict__ w_score,
                                              const float* __restrict__ b_score,
                                              float* __restrict__ out) {
    __shared__ float red[512];
    int t = threadIdx.x, j = blockIdx.x;
    if (j < 128) {
        float v0 = vals[t], v1 = vals[t + 512];
        red[t] = fmaxf(v0, v1);
        __syncthreads();
        for (int s = 256; s > 0; s >>= 1) { if (t < s) red[t] = fmaxf(red[t], red[t + s]); __syncthreads(); }
        float m = red[0];
        __syncthreads();
        red[t] = expf(v0 - m) + expf(v1 - m);
        __syncthreads();
        for (int s = 256; s > 0; s >>= 1) { if (t < s) red[t] += red[t + s]; __syncthreads(); }
        float S = red[0];
        float acc = 0.f;
        #pragma unroll
        for (int k = j * 8; k < j * 8 + 8; ++k) {
            float w = expf(vals[k] - m) / S;
            acc = fmaf(w, hs[(size_t)idx[k] * E_ + t], acc);
        }
        // score piece: (block's attn partial) . w_score[512:1024]
        __syncthreads();
        red[t] = acc * w_score[512 + t];
        __syncthreads();
        for (int s = 256; s > 0; s >>= 1) { if (t < s) red[t] += red[t + s]; __syncthreads(); }
        if (t == 0) atomicAdd(&out[0], red[0]);
    } else {
        // ---- GRU finalize + base score terms ----
        float rr = 1.f / (1.f + expf(-(gi[t] + gh[t])));
        float z = 1.f / (1.f + expf(-(gi[H_ + t] + gh[H_ + t])));
        float n = tanhf(gi[2 * H_ + t] + rr * gh[2 * H_ + t]);
        float hp = h_in[t];
        float hn = (1.f - z) * n + z * hp;
        out[1 + t] = hn;                          // h_new
        out[OUT_HS + (size_t)T_ * E_ + t] = hn;   // hs_new last row
        float d = ws_v[t] * w_score[t] + hp * w_score[1024 + t];
        if (t == 0) d += 1024.0f * w_score[1536] + b_score[0];
        red[t] = d;
        __syncthreads();
        for (int s = 256; s > 0; s >>= 1) { if (t < s) red[t] += red[t + s]; __syncthreads(); }
        if (t == 0) atomicAdd(&out[0], red[0]);
    }
}

extern "C" void kernel_launch(void* const* d_in, const int* in_sizes, int n_in,
                              void* d_out, int out_size, void* d_ws, size_t ws_size,
                              hipStream_t stream) {
    const int*   topic   = (const int*)d_in[0];
    const float* score_s = (const float*)d_in[1];
    const float* emb     = (const float*)d_in[2];
    const float* h_in    = (const float*)d_in[3];
    const float* vs      = (const float*)d_in[4];
    const float* hs      = (const float*)d_in[5];
    const float* w_ih    = (const float*)d_in[6];
    const float* w_hh    = (const float*)d_in[7];
    const float* b_ih    = (const float*)d_in[8];
    const float* b_hh    = (const float*)d_in[9];
    const float* w_score = (const float*)d_in[10];
    const float* b_score = (const float*)d_in[11];
    float* out = (float*)d_out;

    float*    wsf   = (float*)d_ws;
    float*    v_ws  = wsf + OFF_V;
    float*    alpha = wsf + OFF_ALPHA;
    unsigned* hist1 = (unsigned*)(wsf + OFF_HIST1);
    unsigned* cnt   = (unsigned*)(wsf + OFF_CNT);
    float*    vals  = wsf + OFF_VALS;
    int*      idx   = (int*)(wsf + OFF_IDX);
    float*    candv = wsf + OFF_CANDV;
    int*      candi = (int*)(wsf + OFF_CANDI);
    float*    gi    = wsf + OFF_GI;
    float*    gh    = wsf + OFF_GH;

    // 1) v + zero-init (+ out[0] score accumulator)
    hipLaunchKernelGGL(k_init, dim3(66), dim3(1024), 0, stream,
                       topic, emb, v_ws, hist1, out);
    // 2) fused GRU gates + copies + alpha + hist1
    hipLaunchKernelGGL(k_mega, dim3(NB_MEGA), dim3(256), 0, stream,
                       vs, hs, v_ws, alpha, hist1,
                       w_ih, w_hh, b_ih, b_hh, score_s, h_in, gi, gh, out);
    // 3) collect (redundant per-block scan) -> definite top-K + candidates
    hipLaunchKernelGGL(k_collect, dim3(T_ / 256), dim3(256), 0, stream,
                       alpha, hist1, cnt, vals, idx, candv, candi);
    // 4) exact rank-resolve among candidates
    hipLaunchKernelGGL(k_resolve, dim3(1), dim3(256), 0, stream,
                       candv, candi, cnt, vals, idx);
    // 5) softmax + gather + score accumulation + GRU finalize
    hipLaunchKernelGGL(k_attn, dim3(129), dim3(512), 0, stream,
                       hs, vals, idx, gi, gh, h_in, v_ws, w_score, b_score, out);
}

// Round 12
// 220.137 us; speedup vs baseline: 45.2312x; 1.0263x over previous
//
#include <hip/hip_runtime.h>
#include <math.h>

// Problem constants (from reference)
constexpr int T_ = 131072;
constexpr int E_ = 512;
constexpr int H_ = 512;
constexpr int K_ = 1024;
constexpr int L_ = 128;
constexpr int CAND_CAP = 16384;

typedef __attribute__((ext_vector_type(4))) float f32x4;

// Grid sizes
constexpr int NB_GRU = 384;
constexpr unsigned NB_MEGA = NB_GRU + 2 * (T_ / 4);   // 65920

// Workspace layout (element offsets; floats unless noted)
constexpr size_t OFF_V     = 0;                    // 512 f
constexpr size_t OFF_ALPHA = 512;                  // 131072 f
constexpr size_t OFF_HIST1 = OFF_ALPHA + T_;       // 65536 u32
constexpr size_t OFF_CNT   = OFF_HIST1 + 65536;    // 2 u32 (def count, cand count)
constexpr size_t OFF_VALS  = OFF_CNT + 2;          // 1024 f
constexpr size_t OFF_IDX   = OFF_VALS + K_;        // 1024 i32
constexpr size_t OFF_CANDV = OFF_IDX + K_;         // 16384 f
constexpr size_t OFF_CANDI = OFF_CANDV + CAND_CAP; // 16384 i32
constexpr size_t OFF_GI    = OFF_CANDI + CAND_CAP; // 1536 f
constexpr size_t OFF_GH    = OFF_GI + 3 * H_;      // 1536 f

// Zeroed-per-call contiguous region: hist1 + cnt
constexpr int ZERO_N = 65536 + 2;

// Output layout: score(1) | h_new(512) | vs_new((T+1)*512) | hs_new((T+1)*512)
constexpr size_t OUT_VS = 513;
constexpr size_t OUT_HS = 513 + (size_t)(T_ + 1) * E_;

// JOURNAL (measured):
//  R4:  low-cardinality chunk atomic in mega -> 40K-deep serialization, 860us. NEVER.
//  R5:  separate-kernel tail + parallel LDS scans = 244.9us.
//  R6:  spin grid-barriers (512 blocks, cross-XCD) = +43us each. NEVER spin.
//  R7:  mega 2 rows/wave neutral (not issue-depth-limited).
//  R8:  GRU folded into mega as leading blocks = 235.75 (-9).
//  R9:  single radix pass + candidate rank-resolve = 227.56 (-8).
//  R10: last-finisher tickets (fence + device RMW) in 65920 blocks = 9957us.
//       NEVER per-block device fences/tickets in large grids.
//  R11: redundant per-block scan in collect + score-atomic fold = 225.93. GOOD.
//  R4/R10 profile: NT stores preserve L3 input residency (FETCH 267MB). KEEP NT.
//       WRITE=554MB vs 513MB ideal = +8% from per-row partial-line seams.
//  This round: aligned-chunk store repartition in mega (sole change): wave widx
//       stores {row widx-1[511], row widx[0..510]} at an ALIGNED 2KB chunk ->
//       zero partial lines; loads/alpha unchanged; special wave 0 does head/tail.

__device__ __forceinline__ unsigned fkey(float f) {
    unsigned u = __float_as_uint(f);
    return (u & 0x80000000u) ? ~u : (u | 0x80000000u);  // ascending key == ascending float
}

// Last block: v = mean(emb[topic]) (two 512-thread halves, deterministic order)
// + zero out[0] (score accumulator). Other blocks: zero hist1+cnt.
__global__ __launch_bounds__(1024) void k_init(const int* __restrict__ topic,
                                               const float* __restrict__ emb,
                                               float* __restrict__ ws_v,
                                               unsigned* __restrict__ zero_base,
                                               float* __restrict__ out) {
    if (blockIdx.x == gridDim.x - 1) {
        __shared__ float part[512];
        int t = threadIdx.x;
        int e = t & 511, g = t >> 9;       // g in {0,1}
        float s = 0.f;
        #pragma unroll 8
        for (int l = g * 64; l < g * 64 + 64; ++l) {
            int tp = topic[l];
            s += emb[(size_t)tp * E_ + e];
        }
        if (g == 1) part[e] = s;
        __syncthreads();
        if (g == 0) {
            float v = (s + part[e]) * (1.0f / L_);
            ws_v[e] = v;
            out[OUT_VS + (size_t)T_ * E_ + e] = v;  // vs_new last row
            if (e == 0) out[0] = 0.f;               // score accumulator
        }
    } else {
        int i = blockIdx.x * blockDim.x + threadIdx.x;
        if (i < ZERO_N) zero_base[i] = 0u;
    }
}

// Mega kernel: {GRU gates (blocks 0..383)} + {vs half} + {hs half}.
// Each half: wave widx in [0,T) loads SOURCE row widx (aligned NT float4),
// computes alpha dot (vs half). STORES are repartitioned by aligned DEST
// chunks: wave widx>=1 stores chunk [regbase-1+512*widx, +512) =
// {row widx-1 el 511 (uniform scalar load), row widx els 0..510} -> all
// full-line aligned NT stores, zero partial lines (R11: seams cost +8% WRITE).
// Wave widx==0 stores row 0 els 0..510 + the region tail element (scalar).
__global__ __launch_bounds__(256) void k_mega(const float* __restrict__ vs,
                                              const float* __restrict__ hs,
                                              const float* __restrict__ ws_v,
                                              float* __restrict__ alpha,
                                              unsigned* __restrict__ hist1,
                                              const float* __restrict__ wih,
                                              const float* __restrict__ whh,
                                              const float* __restrict__ bih,
                                              const float* __restrict__ bhh,
                                              const float* __restrict__ score_s,
                                              const float* __restrict__ h_in,
                                              float* __restrict__ gi,
                                              float* __restrict__ gh,
                                              float* __restrict__ out) {
    __shared__ float x[1025 + 512];
    int t = threadIdx.x;
    int wave = t >> 6, lane = t & 63;
    int b = blockIdx.x;
    if (b < NB_GRU) {
        // ---- GRU gates: one gate-row per wave ----
        float ss = score_s[0];
        float pos = ss >= 0.5f ? 1.f : 0.f;
        for (int c = t; c < 1025; c += 256) {
            float xv;
            if (c < 512)       xv = ws_v[c] * pos;
            else if (c < 1024) xv = ws_v[c - 512] * (1.f - pos);
            else               xv = ss;
            x[c] = xv;
        }
        for (int c = t; c < 512; c += 256) x[1025 + c] = h_in[c];
        __syncthreads();
        int row = b * 4 + wave;
        const float* wr = wih + (size_t)row * 1025;
        float s1 = 0.f;
        for (int c = lane; c < 1025; c += 64) s1 = fmaf(wr[c], x[c], s1);
        const float* hr = whh + (size_t)row * 512;
        float s2 = 0.f;
        #pragma unroll
        for (int c = lane; c < 512; c += 64) s2 = fmaf(hr[c], x[1025 + c], s2);
        #pragma unroll
        for (int m = 32; m; m >>= 1) {
            s1 += __shfl_xor(s1, m, 64);
            s2 += __shfl_xor(s2, m, 64);
        }
        if (lane == 0) { gi[row] = s1 + bih[row]; gh[row] = s2 + bhh[row]; }
        return;
    }
    // ---- Copy + alpha halves ----
    b -= NB_GRU;
    bool is_vs = b < (T_ / 4);
    int widx = (is_vs ? b : b - T_ / 4) * 4 + wave;   // source row / chunk index
    const float* src_base = is_vs ? vs : hs;
    size_t regbase = is_vs ? OUT_VS : OUT_HS;
    const f32x4* src4 = (const f32x4*)(src_base + (size_t)widx * E_);
    f32x4 a0 = __builtin_nontemporal_load(&src4[lane]);
    f32x4 a1 = __builtin_nontemporal_load(&src4[lane + 64]);
    if (is_vs) {
        const f32x4* v4 = (const f32x4*)ws_v;
        f32x4 b0 = v4[lane];
        f32x4 b1 = v4[lane + 64];
        float dot = 0.f;
        dot = fmaf(a0.x, b0.x, dot); dot = fmaf(a0.y, b0.y, dot);
        dot = fmaf(a0.z, b0.z, dot); dot = fmaf(a0.w, b0.w, dot);
        dot = fmaf(a1.x, b1.x, dot); dot = fmaf(a1.y, b1.y, dot);
        dot = fmaf(a1.z, b1.z, dot); dot = fmaf(a1.w, b1.w, dot);
        #pragma unroll
        for (int m = 32; m; m >>= 1) dot += __shfl_xor(dot, m, 64);
        if (lane == 0) {
            alpha[widx] = dot;
            atomicAdd(&hist1[fkey(dot) >> 16], 1u);
        }
    }
    if (widx == 0) {
        // ---- special wave: row 0 els 0..510 (scalar NT) + region tail ----
        float* dst0 = out + regbase;
        #pragma unroll
        for (int k = 0; k < 4; ++k) {
            int j = 4 * lane + k;
            __builtin_nontemporal_store(((const float*)&a0)[k], &dst0[j]);
            int j2 = 256 + 4 * lane + k;
            if (j2 < 511)
                __builtin_nontemporal_store(((const float*)&a1)[k], &dst0[j2]);
        }
        if (lane == 0) {
            // region tail: row T-1 el 511 -> out[regbase - 1 + 512*T]
            float tl = src_base[(size_t)T_ * E_ - 1];
            __builtin_nontemporal_store(tl, &out[regbase - 1 + (size_t)T_ * E_]);
        }
    } else {
        // ---- aligned-chunk store: {prev row el 511, this row els 0..510} ----
        int pl = (lane + 63) & 63;
        float p0w = __shfl(a0.w, pl, 64);
        float p1w = __shfl(a1.w, pl, 64);
        float prevel = src_base[(size_t)widx * E_ - 1];   // wave-uniform scalar load
        f32x4* d4 = (f32x4*)(out + regbase - 1 + (size_t)widx * E_);  // 16B-aligned
        f32x4 lo, hi;
        lo.x = (lane == 0) ? prevel : p0w;
        lo.y = a0.x; lo.z = a0.y; lo.w = a0.z;
        hi.x = (lane == 0) ? p0w : p1w;   // lane 0: el 255 = lane 63's a0.w
        hi.y = a1.x; hi.z = a1.y; hi.w = a1.z;
        __builtin_nontemporal_store(lo, &d4[lane]);
        __builtin_nontemporal_store(hi, &d4[lane + 64]);
    }
}

// Collect pass with REDUNDANT per-block scan (R11-verified): every block
// computes bin1 from hist1 (L2-resident), then classifies its 256 elements.
__global__ __launch_bounds__(256) void k_collect(const float* __restrict__ alpha,
                                                 const unsigned* __restrict__ hist1,
                                                 unsigned* __restrict__ cnt,
                                                 float* __restrict__ vals,
                                                 int* __restrict__ idx,
                                                 float* __restrict__ candv,
                                                 int* __restrict__ candi) {
    __shared__ unsigned ps[258];
    int t = threadIdx.x;
    // ---- redundant scan: find bin1 (bin containing the Kth largest) ----
    unsigned base = 65536u - (unsigned)(t + 1) * 256u;
    unsigned s = 0;
    for (int j = 0; j < 256; ++j) s += hist1[base + j];
    ps[t] = s;
    __syncthreads();
    #pragma unroll
    for (int off = 1; off < 256; off <<= 1) {
        unsigned v = (t >= off) ? ps[t - off] : 0u;
        __syncthreads();
        ps[t] += v;
        __syncthreads();
    }
    unsigned incl = ps[t], excl = incl - s;
    if (excl < (unsigned)K_ && incl >= (unsigned)K_) { ps[256] = (unsigned)t; ps[257] = excl; }
    __syncthreads();
    unsigned c = ps[256];
    unsigned Kw2 = (unsigned)K_ - ps[257];
    unsigned bin = 65535u - c * 256u - (unsigned)t;
    unsigned bv = hist1[bin];
    __syncthreads();
    ps[t] = bv;
    __syncthreads();
    #pragma unroll
    for (int off = 1; off < 256; off <<= 1) {
        unsigned v = (t >= off) ? ps[t - off] : 0u;
        __syncthreads();
        ps[t] += v;
        __syncthreads();
    }
    unsigned inc2 = ps[t], ex2 = inc2 - bv;
    if (ex2 < Kw2 && inc2 >= Kw2) ps[256] = bin;   // winner publishes bin1
    __syncthreads();
    unsigned bin1 = ps[256];
    // ---- classify this block's 256 elements ----
    int i = blockIdx.x * 256 + t;
    float a = alpha[i];
    unsigned hb = fkey(a) >> 16;
    if (hb > bin1) {
        unsigned p = atomicAdd(&cnt[0], 1u);
        vals[p] = a; idx[p] = i;
    } else if (hb == bin1) {
        unsigned q = atomicAdd(&cnt[1], 1u);
        if (q < (unsigned)CAND_CAP) { candv[q] = a; candi[q] = i; }
    }
}

// Exact stable-rank selection among candidates (O(nc^2), nc ~ tens).
__global__ __launch_bounds__(256) void k_resolve(const float* __restrict__ candv,
                                                 const int* __restrict__ candi,
                                                 const unsigned* __restrict__ cnt,
                                                 float* __restrict__ vals,
                                                 int* __restrict__ idx) {
    int t = threadIdx.x;
    unsigned nc = cnt[1] < (unsigned)CAND_CAP ? cnt[1] : (unsigned)CAND_CAP;
    unsigned ndef = cnt[0];
    unsigned k2 = (unsigned)K_ - ndef;
    for (unsigned i = t; i < nc; i += 256) {
        unsigned ki = fkey(candv[i]);
        unsigned greater = 0, eqb = 0;
        for (unsigned j = 0; j < nc; ++j) {
            unsigned kj = fkey(candv[j]);
            greater += (kj > ki) ? 1u : 0u;
            eqb += (kj == ki && j < i) ? 1u : 0u;
        }
        unsigned r = greater + eqb;
        if (r < k2) { vals[ndef + r] = candv[i]; idx[ndef + r] = candi[i]; }
    }
}

// Fused softmax + attention gather + score accumulation + GRU finalize
// (R11-verified). Blocks 0..127: gather + score piece -> atomicAdd out[0].
// Block 128: GRU finalize + base score terms -> atomicAdd out[0].
__global__ __launch_bounds__(512) void k_attn(const float* __restrict__ hs,
                                              const float* __restrict__ vals,
                                              const int* __restrict__ idx,
                                              const float* __restrict__ gi,
                                              const float* __restrict__ gh,
                                              const float* __restrict__ h_in,
                                              const float* __restrict__ ws_v,
                                              const float* __restrict__ w_score,
                                              const float* __restrict__ b_score,
                                              float* __restrict__ out) {
    __shared__ float red[512];
    int t = threadIdx.x, j = blockIdx.x;
    if (j < 128) {
        float v0 = vals[t], v1 = vals[t + 512];
        red[t] = fmaxf(v0, v1);
        __syncthreads();
        for (int s = 256; s > 0; s >>= 1) { if (t < s) red[t] = fmaxf(red[t], red[t + s]); __syncthreads(); }
        float m = red[0];
        __syncthreads();
        red[t] = expf(v0 - m) + expf(v1 - m);
        __syncthreads();
        for (int s = 256; s > 0; s >>= 1) { if (t < s) red[t] += red[t + s]; __syncthreads(); }
        float S = red[0];
        float acc = 0.f;
        #pragma unroll
        for (int k = j * 8; k < j * 8 + 8; ++k) {
            float w = expf(vals[k] - m) / S;
            acc = fmaf(w, hs[(size_t)idx[k] * E_ + t], acc);
        }
        // score piece: (block's attn partial) . w_score[512:1024]
        __syncthreads();
        red[t] = acc * w_score[512 + t];
        __syncthreads();
        for (int s = 256; s > 0; s >>= 1) { if (t < s) red[t] += red[t + s]; __syncthreads(); }
        if (t == 0) atomicAdd(&out[0], red[0]);
    } else {
        // ---- GRU finalize + base score terms ----
        float rr = 1.f / (1.f + expf(-(gi[t] + gh[t])));
        float z = 1.f / (1.f + expf(-(gi[H_ + t] + gh[H_ + t])));
        float n = tanhf(gi[2 * H_ + t] + rr * gh[2 * H_ + t]);
        float hp = h_in[t];
        float hn = (1.f - z) * n + z * hp;
        out[1 + t] = hn;                          // h_new
        out[OUT_HS + (size_t)T_ * E_ + t] = hn;   // hs_new last row
        float d = ws_v[t] * w_score[t] + hp * w_score[1024 + t];
        if (t == 0) d += 1024.0f * w_score[1536] + b_score[0];
        red[t] = d;
        __syncthreads();
        for (int s = 256; s > 0; s >>= 1) { if (t < s) red[t] += red[t + s]; __syncthreads(); }
        if (t == 0) atomicAdd(&out[0], red[0]);
    }
}

extern "C" void kernel_launch(void* const* d_in, const int* in_sizes, int n_in,
                              void* d_out, int out_size, void* d_ws, size_t ws_size,
                              hipStream_t stream) {
    const int*   topic   = (const int*)d_in[0];
    const float* score_s = (const float*)d_in[1];
    const float* emb     = (const float*)d_in[2];
    const float* h_in    = (const float*)d_in[3];
    const float* vs      = (const float*)d_in[4];
    const float* hs      = (const float*)d_in[5];
    const float* w_ih    = (const float*)d_in[6];
    const float* w_hh    = (const float*)d_in[7];
    const float* b_ih    = (const float*)d_in[8];
    const float* b_hh    = (const float*)d_in[9];
    const float* w_score = (const float*)d_in[10];
    const float* b_score = (const float*)d_in[11];
    float* out = (float*)d_out;

    float*    wsf   = (float*)d_ws;
    float*    v_ws  = wsf + OFF_V;
    float*    alpha = wsf + OFF_ALPHA;
    unsigned* hist1 = (unsigned*)(wsf + OFF_HIST1);
    unsigned* cnt   = (unsigned*)(wsf + OFF_CNT);
    float*    vals  = wsf + OFF_VALS;
    int*      idx   = (int*)(wsf + OFF_IDX);
    float*    candv = wsf + OFF_CANDV;
    int*      candi = (int*)(wsf + OFF_CANDI);
    float*    gi    = wsf + OFF_GI;
    float*    gh    = wsf + OFF_GH;

    // 1) v + zero-init (+ out[0] score accumulator)
    hipLaunchKernelGGL(k_init, dim3(66), dim3(1024), 0, stream,
                       topic, emb, v_ws, hist1, out);
    // 2) fused GRU gates + copies (aligned-chunk stores) + alpha + hist1
    hipLaunchKernelGGL(k_mega, dim3(NB_MEGA), dim3(256), 0, stream,
                       vs, hs, v_ws, alpha, hist1,
                       w_ih, w_hh, b_ih, b_hh, score_s, h_in, gi, gh, out);
    // 3) collect (redundant per-block scan) -> definite top-K + candidates
    hipLaunchKernelGGL(k_collect, dim3(T_ / 256), dim3(256), 0, stream,
                       alpha, hist1, cnt, vals, idx, candv, candi);
    // 4) exact rank-resolve among candidates
    hipLaunchKernelGGL(k_resolve, dim3(1), dim3(256), 0, stream,
                       candv, candi, cnt, vals, idx);
    // 5) softmax + gather + score accumulation + GRU finalize
    hipLaunchKernelGGL(k_attn, dim3(129), dim3(512), 0, stream,
                       hs, vals, idx, gi, gh, h_in, v_ws, w_score, b_score, out);
}

// Round 13
// 219.469 us; speedup vs baseline: 45.3689x; 1.0030x over previous
//
#include <hip/hip_runtime.h>
#include <math.h>

// Problem constants (from reference)
constexpr int T_ = 131072;
constexpr int E_ = 512;
constexpr int H_ = 512;
constexpr int K_ = 1024;
constexpr int L_ = 128;
constexpr int CAND_CAP = 16384;

typedef __attribute__((ext_vector_type(4))) float f32x4;

// Grid sizes
constexpr int NB_GRU = 384;
constexpr unsigned NB_MEGA = NB_GRU + 2 * (T_ / 4);   // 65920

// Workspace layout (element offsets; floats unless noted)
constexpr size_t OFF_V     = 0;                    // 512 f
constexpr size_t OFF_ALPHA = 512;                  // 131072 f
constexpr size_t OFF_HIST1 = OFF_ALPHA + T_;       // 65536 u32
constexpr size_t OFF_CNT   = OFF_HIST1 + 65536;    // 2 u32 (def count, cand count)
constexpr size_t OFF_VALS  = OFF_CNT + 2;          // 1024 f
constexpr size_t OFF_IDX   = OFF_VALS + K_;        // 1024 i32
constexpr size_t OFF_CANDV = OFF_IDX + K_;         // 16384 f
constexpr size_t OFF_CANDI = OFF_CANDV + CAND_CAP; // 16384 i32
constexpr size_t OFF_GI    = OFF_CANDI + CAND_CAP; // 1536 f
constexpr size_t OFF_GH    = OFF_GI + 3 * H_;      // 1536 f

// Zeroed-per-call contiguous region: hist1 + cnt
constexpr int ZERO_N = 65536 + 2;

// Output layout: score(1) | h_new(512) | vs_new((T+1)*512) | hs_new((T+1)*512)
constexpr size_t OUT_VS = 513;
constexpr size_t OUT_HS = 513 + (size_t)(T_ + 1) * E_;

// JOURNAL (measured):
//  R4:  low-cardinality chunk atomic in mega -> 40K-deep serialization, 860us. NEVER.
//  R5:  separate-kernel tail + parallel LDS scans = 244.9us.
//  R6:  spin grid-barriers (512 blocks, cross-XCD) = +43us each. NEVER spin.
//  R7:  mega 2 rows/wave neutral (not issue-depth-limited).
//  R8:  GRU folded into mega as leading blocks = 235.75 (-9).
//  R9:  single radix pass + candidate rank-resolve = 227.56 (-8).
//  R10: last-finisher tickets (fence + device RMW) in 65920 blocks = 9957us.
//       NEVER per-block device fences/tickets in large grids.
//  R11: redundant per-block scan in collect + score-atomic fold = 225.93.
//  R12: aligned-chunk stores (zero partial lines) = 220.14 (-5.8). Mega ~183us
//       = ~5.6 TB/s memory-system rate = 89% of 6.29 TB/s copy ceiling.
//  R4/R10 profile: NT stores preserve L3 input residency (FETCH 267MB). KEEP NT.
//  This round: (a) resolve folded into attn via redundant per-block rank-resolve
//       (R11 redundancy pattern, NO tickets), (b) uint4 chunk-sum in collect.

__device__ __forceinline__ unsigned fkey(float f) {
    unsigned u = __float_as_uint(f);
    return (u & 0x80000000u) ? ~u : (u | 0x80000000u);  // ascending key == ascending float
}

// Last block: v = mean(emb[topic]) (two 512-thread halves, deterministic order)
// + zero out[0] (score accumulator). Other blocks: zero hist1+cnt.
__global__ __launch_bounds__(1024) void k_init(const int* __restrict__ topic,
                                               const float* __restrict__ emb,
                                               float* __restrict__ ws_v,
                                               unsigned* __restrict__ zero_base,
                                               float* __restrict__ out) {
    if (blockIdx.x == gridDim.x - 1) {
        __shared__ float part[512];
        int t = threadIdx.x;
        int e = t & 511, g = t >> 9;       // g in {0,1}
        float s = 0.f;
        #pragma unroll 8
        for (int l = g * 64; l < g * 64 + 64; ++l) {
            int tp = topic[l];
            s += emb[(size_t)tp * E_ + e];
        }
        if (g == 1) part[e] = s;
        __syncthreads();
        if (g == 0) {
            float v = (s + part[e]) * (1.0f / L_);
            ws_v[e] = v;
            out[OUT_VS + (size_t)T_ * E_ + e] = v;  // vs_new last row
            if (e == 0) out[0] = 0.f;               // score accumulator
        }
    } else {
        int i = blockIdx.x * blockDim.x + threadIdx.x;
        if (i < ZERO_N) zero_base[i] = 0u;
    }
}

// Mega kernel (R12-verified, byte-identical): {GRU gates} + {vs half + alpha +
// hist1} + {hs half}. NT loads+stores; aligned-chunk store repartition (wave
// widx stores {row widx-1[511], row widx[0..510]} at an aligned 2KB chunk).
__global__ __launch_bounds__(256) void k_mega(const float* __restrict__ vs,
                                              const float* __restrict__ hs,
                                              const float* __restrict__ ws_v,
                                              float* __restrict__ alpha,
                                              unsigned* __restrict__ hist1,
                                              const float* __restrict__ wih,
                                              const float* __restrict__ whh,
                                              const float* __restrict__ bih,
                                              const float* __restrict__ bhh,
                                              const float* __restrict__ score_s,
                                              const float* __restrict__ h_in,
                                              float* __restrict__ gi,
                                              float* __restrict__ gh,
                                              float* __restrict__ out) {
    __shared__ float x[1025 + 512];
    int t = threadIdx.x;
    int wave = t >> 6, lane = t & 63;
    int b = blockIdx.x;
    if (b < NB_GRU) {
        // ---- GRU gates: one gate-row per wave ----
        float ss = score_s[0];
        float pos = ss >= 0.5f ? 1.f : 0.f;
        for (int c = t; c < 1025; c += 256) {
            float xv;
            if (c < 512)       xv = ws_v[c] * pos;
            else if (c < 1024) xv = ws_v[c - 512] * (1.f - pos);
            else               xv = ss;
            x[c] = xv;
        }
        for (int c = t; c < 512; c += 256) x[1025 + c] = h_in[c];
        __syncthreads();
        int row = b * 4 + wave;
        const float* wr = wih + (size_t)row * 1025;
        float s1 = 0.f;
        for (int c = lane; c < 1025; c += 64) s1 = fmaf(wr[c], x[c], s1);
        const float* hr = whh + (size_t)row * 512;
        float s2 = 0.f;
        #pragma unroll
        for (int c = lane; c < 512; c += 64) s2 = fmaf(hr[c], x[1025 + c], s2);
        #pragma unroll
        for (int m = 32; m; m >>= 1) {
            s1 += __shfl_xor(s1, m, 64);
            s2 += __shfl_xor(s2, m, 64);
        }
        if (lane == 0) { gi[row] = s1 + bih[row]; gh[row] = s2 + bhh[row]; }
        return;
    }
    // ---- Copy + alpha halves ----
    b -= NB_GRU;
    bool is_vs = b < (T_ / 4);
    int widx = (is_vs ? b : b - T_ / 4) * 4 + wave;   // source row / chunk index
    const float* src_base = is_vs ? vs : hs;
    size_t regbase = is_vs ? OUT_VS : OUT_HS;
    const f32x4* src4 = (const f32x4*)(src_base + (size_t)widx * E_);
    f32x4 a0 = __builtin_nontemporal_load(&src4[lane]);
    f32x4 a1 = __builtin_nontemporal_load(&src4[lane + 64]);
    if (is_vs) {
        const f32x4* v4 = (const f32x4*)ws_v;
        f32x4 b0 = v4[lane];
        f32x4 b1 = v4[lane + 64];
        float dot = 0.f;
        dot = fmaf(a0.x, b0.x, dot); dot = fmaf(a0.y, b0.y, dot);
        dot = fmaf(a0.z, b0.z, dot); dot = fmaf(a0.w, b0.w, dot);
        dot = fmaf(a1.x, b1.x, dot); dot = fmaf(a1.y, b1.y, dot);
        dot = fmaf(a1.z, b1.z, dot); dot = fmaf(a1.w, b1.w, dot);
        #pragma unroll
        for (int m = 32; m; m >>= 1) dot += __shfl_xor(dot, m, 64);
        if (lane == 0) {
            alpha[widx] = dot;
            atomicAdd(&hist1[fkey(dot) >> 16], 1u);
        }
    }
    if (widx == 0) {
        // ---- special wave: row 0 els 0..510 (scalar NT) + region tail ----
        float* dst0 = out + regbase;
        #pragma unroll
        for (int k = 0; k < 4; ++k) {
            int j = 4 * lane + k;
            __builtin_nontemporal_store(((const float*)&a0)[k], &dst0[j]);
            int j2 = 256 + 4 * lane + k;
            if (j2 < 511)
                __builtin_nontemporal_store(((const float*)&a1)[k], &dst0[j2]);
        }
        if (lane == 0) {
            // region tail: row T-1 el 511 -> out[regbase - 1 + 512*T]
            float tl = src_base[(size_t)T_ * E_ - 1];
            __builtin_nontemporal_store(tl, &out[regbase - 1 + (size_t)T_ * E_]);
        }
    } else {
        // ---- aligned-chunk store: {prev row el 511, this row els 0..510} ----
        int pl = (lane + 63) & 63;
        float p0w = __shfl(a0.w, pl, 64);
        float p1w = __shfl(a1.w, pl, 64);
        float prevel = src_base[(size_t)widx * E_ - 1];   // wave-uniform scalar load
        f32x4* d4 = (f32x4*)(out + regbase - 1 + (size_t)widx * E_);  // 16B-aligned
        f32x4 lo, hi;
        lo.x = (lane == 0) ? prevel : p0w;
        lo.y = a0.x; lo.z = a0.y; lo.w = a0.z;
        hi.x = (lane == 0) ? p0w : p1w;   // lane 0: el 255 = lane 63's a0.w
        hi.y = a1.x; hi.z = a1.y; hi.w = a1.z;
        __builtin_nontemporal_store(lo, &d4[lane]);
        __builtin_nontemporal_store(hi, &d4[lane + 64]);
    }
}

// Collect pass with REDUNDANT per-block scan (R11-verified): every block
// computes bin1 from hist1 (L2-resident, uint4-vectorized chunk sums), then
// classifies its 256 elements.
__global__ __launch_bounds__(256) void k_collect(const float* __restrict__ alpha,
                                                 const unsigned* __restrict__ hist1,
                                                 unsigned* __restrict__ cnt,
                                                 float* __restrict__ vals,
                                                 int* __restrict__ idx,
                                                 float* __restrict__ candv,
                                                 int* __restrict__ candi) {
    __shared__ unsigned ps[258];
    int t = threadIdx.x;
    // ---- redundant scan: find bin1 (bin containing the Kth largest) ----
    unsigned base = 65536u - (unsigned)(t + 1) * 256u;   // multiple of 256 -> 1KB aligned
    const uint4* h4 = (const uint4*)(hist1 + base);
    unsigned s = 0;
    #pragma unroll 8
    for (int j = 0; j < 64; ++j) {
        uint4 v = h4[j];
        s += v.x + v.y + v.z + v.w;
    }
    ps[t] = s;
    __syncthreads();
    #pragma unroll
    for (int off = 1; off < 256; off <<= 1) {
        unsigned v = (t >= off) ? ps[t - off] : 0u;
        __syncthreads();
        ps[t] += v;
        __syncthreads();
    }
    unsigned incl = ps[t], excl = incl - s;
    if (excl < (unsigned)K_ && incl >= (unsigned)K_) { ps[256] = (unsigned)t; ps[257] = excl; }
    __syncthreads();
    unsigned c = ps[256];
    unsigned Kw2 = (unsigned)K_ - ps[257];
    unsigned bin = 65535u - c * 256u - (unsigned)t;
    unsigned bv = hist1[bin];
    __syncthreads();
    ps[t] = bv;
    __syncthreads();
    #pragma unroll
    for (int off = 1; off < 256; off <<= 1) {
        unsigned v = (t >= off) ? ps[t - off] : 0u;
        __syncthreads();
        ps[t] += v;
        __syncthreads();
    }
    unsigned inc2 = ps[t], ex2 = inc2 - bv;
    if (ex2 < Kw2 && inc2 >= Kw2) ps[256] = bin;   // winner publishes bin1
    __syncthreads();
    unsigned bin1 = ps[256];
    // ---- classify this block's 256 elements ----
    int i = blockIdx.x * 256 + t;
    float a = alpha[i];
    unsigned hb = fkey(a) >> 16;
    if (hb > bin1) {
        unsigned p = atomicAdd(&cnt[0], 1u);
        vals[p] = a; idx[p] = i;
    } else if (hb == bin1) {
        unsigned q = atomicAdd(&cnt[1], 1u);
        if (q < (unsigned)CAND_CAP) { candv[q] = a; candi[q] = i; }
    }
}

// Fused {redundant rank-resolve} + softmax + attention gather + score
// accumulation + GRU finalize. Blocks 0..127: build the full sorted-tail
// vals/idx in LDS (definite part from global + redundant O(nc^2) candidate
// resolve, nc ~ tens - R11 redundancy pattern, NO tickets), then softmax +
// gather 8 rows + score piece -> atomicAdd out[0].
// Block 128: GRU finalize + base score terms -> atomicAdd out[0].
__global__ __launch_bounds__(512) void k_attn(const float* __restrict__ hs,
                                              const float* __restrict__ vals,
                                              const int* __restrict__ idx,
                                              const float* __restrict__ candv,
                                              const int* __restrict__ candi,
                                              const unsigned* __restrict__ cnt,
                                              const float* __restrict__ gi,
                                              const float* __restrict__ gh,
                                              const float* __restrict__ h_in,
                                              const float* __restrict__ ws_v,
                                              const float* __restrict__ w_score,
                                              const float* __restrict__ b_score,
                                              float* __restrict__ out) {
    __shared__ float red[512];
    int t = threadIdx.x, j = blockIdx.x;
    if (j < 128) {
        __shared__ float sv[1024];
        __shared__ int   si[1024];
        unsigned ndef = cnt[0];
        unsigned nc = cnt[1] < (unsigned)CAND_CAP ? cnt[1] : (unsigned)CAND_CAP;
        unsigned k2 = (unsigned)K_ - ndef;
        // definite part from global
        for (unsigned i = t; i < ndef; i += 512) { sv[i] = vals[i]; si[i] = idx[i]; }
        // redundant candidate rank-resolve (deterministic: same buffer order)
        for (unsigned i = t; i < nc; i += 512) {
            float cv = candv[i];
            unsigned ki = fkey(cv);
            unsigned greater = 0, eqb = 0;
            for (unsigned jj = 0; jj < nc; ++jj) {
                unsigned kj = fkey(candv[jj]);
                greater += (kj > ki) ? 1u : 0u;
                eqb += (kj == ki && jj < i) ? 1u : 0u;
            }
            unsigned r = greater + eqb;
            if (r < k2) { sv[ndef + r] = cv; si[ndef + r] = candi[i]; }
        }
        __syncthreads();
        // softmax over sv[0..1024)
        float v0 = sv[t], v1 = sv[t + 512];
        red[t] = fmaxf(v0, v1);
        __syncthreads();
        for (int s = 256; s > 0; s >>= 1) { if (t < s) red[t] = fmaxf(red[t], red[t + s]); __syncthreads(); }
        float m = red[0];
        __syncthreads();
        red[t] = expf(v0 - m) + expf(v1 - m);
        __syncthreads();
        for (int s = 256; s > 0; s >>= 1) { if (t < s) red[t] += red[t + s]; __syncthreads(); }
        float S = red[0];
        float acc = 0.f;
        #pragma unroll
        for (int k = j * 8; k < j * 8 + 8; ++k) {
            float w = expf(sv[k] - m) / S;
            acc = fmaf(w, hs[(size_t)si[k] * E_ + t], acc);
        }
        // score piece: (block's attn partial) . w_score[512:1024]
        __syncthreads();
        red[t] = acc * w_score[512 + t];
        __syncthreads();
        for (int s = 256; s > 0; s >>= 1) { if (t < s) red[t] += red[t + s]; __syncthreads(); }
        if (t == 0) atomicAdd(&out[0], red[0]);
    } else {
        // ---- GRU finalize + base score terms ----
        float rr = 1.f / (1.f + expf(-(gi[t] + gh[t])));
        float z = 1.f / (1.f + expf(-(gi[H_ + t] + gh[H_ + t])));
        float n = tanhf(gi[2 * H_ + t] + rr * gh[2 * H_ + t]);
        float hp = h_in[t];
        float hn = (1.f - z) * n + z * hp;
        out[1 + t] = hn;                          // h_new
        out[OUT_HS + (size_t)T_ * E_ + t] = hn;   // hs_new last row
        float d = ws_v[t] * w_score[t] + hp * w_score[1024 + t];
        if (t == 0) d += 1024.0f * w_score[1536] + b_score[0];
        red[t] = d;
        __syncthreads();
        for (int s = 256; s > 0; s >>= 1) { if (t < s) red[t] += red[t + s]; __syncthreads(); }
        if (t == 0) atomicAdd(&out[0], red[0]);
    }
}

extern "C" void kernel_launch(void* const* d_in, const int* in_sizes, int n_in,
                              void* d_out, int out_size, void* d_ws, size_t ws_size,
                              hipStream_t stream) {
    const int*   topic   = (const int*)d_in[0];
    const float* score_s = (const float*)d_in[1];
    const float* emb     = (const float*)d_in[2];
    const float* h_in    = (const float*)d_in[3];
    const float* vs      = (const float*)d_in[4];
    const float* hs      = (const float*)d_in[5];
    const float* w_ih    = (const float*)d_in[6];
    const float* w_hh    = (const float*)d_in[7];
    const float* b_ih    = (const float*)d_in[8];
    const float* b_hh    = (const float*)d_in[9];
    const float* w_score = (const float*)d_in[10];
    const float* b_score = (const float*)d_in[11];
    float* out = (float*)d_out;

    float*    wsf   = (float*)d_ws;
    float*    v_ws  = wsf + OFF_V;
    float*    alpha = wsf + OFF_ALPHA;
    unsigned* hist1 = (unsigned*)(wsf + OFF_HIST1);
    unsigned* cnt   = (unsigned*)(wsf + OFF_CNT);
    float*    vals  = wsf + OFF_VALS;
    int*      idx   = (int*)(wsf + OFF_IDX);
    float*    candv = wsf + OFF_CANDV;
    int*      candi = (int*)(wsf + OFF_CANDI);
    float*    gi    = wsf + OFF_GI;
    float*    gh    = wsf + OFF_GH;

    // 1) v + zero-init (+ out[0] score accumulator)
    hipLaunchKernelGGL(k_init, dim3(66), dim3(1024), 0, stream,
                       topic, emb, v_ws, hist1, out);
    // 2) fused GRU gates + copies (aligned-chunk stores) + alpha + hist1
    hipLaunchKernelGGL(k_mega, dim3(NB_MEGA), dim3(256), 0, stream,
                       vs, hs, v_ws, alpha, hist1,
                       w_ih, w_hh, b_ih, b_hh, score_s, h_in, gi, gh, out);
    // 3) collect (redundant per-block scan) -> definite top-K + candidates
    hipLaunchKernelGGL(k_collect, dim3(T_ / 256), dim3(256), 0, stream,
                       alpha, hist1, cnt, vals, idx, candv, candi);
    // 4) redundant rank-resolve + softmax + gather + score + GRU finalize
    hipLaunchKernelGGL(k_attn, dim3(129), dim3(512), 0, stream,
                       hs, vals, idx, candv, candi, cnt,
                       gi, gh, h_in, v_ws, w_score, b_score, out);
}